// Round 3
// baseline (16583.882 us; speedup 1.0000x reference)
//
#include <hip/hip_runtime.h>
#include <cstdint>
#include <cstddef>

typedef unsigned short u16;
typedef unsigned int u32;
typedef unsigned long long u64;
typedef short bf16x8 __attribute__((ext_vector_type(8)));
typedef float f32x4 __attribute__((ext_vector_type(4)));
typedef unsigned short u16x4 __attribute__((ext_vector_type(4)));

#define T_LEN 1200

// workspace byte offsets (all 256-aligned). Total ~48.0 MB.
#define O_X     0ull           // x bf16: 38400*512*2        = 39,321,600
#define O_WIH   39321600ull    // W_ih cat bf16: 4096*512*2  =  4,194,304
#define O_WHH   43515904ull    // W_hh cat bf16: 4096*512*2  =  4,194,304
#define O_BIAS  47710208ull    // bias cat f32: 4096*4       =     16,384
#define O_HBUF  47726592ull    // tagged h dwords: 2 par * 2 dir * 32*512 * 4B = 262,144
#define O_CTL   47988736ull    // control: roster[8], dirAssign[8], dirCtr, done
#define WS_NEED 47989248ull

#define HO 19660800ull   // h_n offset in d_out (floats)
#define CO 19693568ull   // c_n offset in d_out (floats)

#define HROW 516         // padded LDS row stride (u16 elems): +4 pad -> cheap banks

__device__ __forceinline__ u16 f2bf(float f) {
  union { float f; unsigned u; } v; v.f = f;
  unsigned r = v.u + 0x7FFFu + ((v.u >> 16) & 1u);
  return (u16)(r >> 16);
}
__device__ __forceinline__ float sigm(float x) { return 1.f / (1.f + __expf(-x)); }
__device__ __forceinline__ float tanh_s(float x) {
  float ax = fabsf(x);
  float e = __expf(-2.f * ax);          // in (0,1], no overflow
  float t = (1.f - e) / (1.f + e);
  return x < 0.f ? -t : t;
}

// ---------------- cast x (f32 -> bf16), 4 elems/thread ----------------
__global__ __launch_bounds__(256) void cast_x_k(const float4* __restrict__ x,
                                                u16* __restrict__ xb) {
  int i = blockIdx.x * 256 + threadIdx.x;   // 4,915,200 threads
  float4 v = x[i];
  u16x4 o;
  o.x = f2bf(v.x); o.y = f2bf(v.y); o.z = f2bf(v.z); o.w = f2bf(v.w);
  *(u16x4*)(xb + (size_t)i * 4) = o;
}

// ---------------- concat + cast weights, fold biases ----------------
__global__ __launch_bounds__(256) void prep_w_k(
    const float* __restrict__ wih_f, const float* __restrict__ whh_f,
    const float* __restrict__ bih_f, const float* __restrict__ bhh_f,
    const float* __restrict__ wih_b, const float* __restrict__ whh_b,
    const float* __restrict__ bih_b, const float* __restrict__ bhh_b,
    u16* __restrict__ Wih, u16* __restrict__ Whh, float* __restrict__ bias) {
  int tid = blockIdx.x * 256 + threadIdx.x;   // 0 .. 4096*512-1
  int g = tid >> 9;
  float vi, vh;
  if (g < 2048) { vi = wih_f[tid]; vh = whh_f[tid]; }
  else { int t2 = tid - (2048 * 512); vi = wih_b[t2]; vh = whh_b[t2]; }
  Wih[tid] = f2bf(vi);
  Whh[tid] = f2bf(vh);
  if ((tid & 511) == 0) {
    bias[g] = (g < 2048) ? (bih_f[g] + bhh_f[g]) : (bih_b[g - 2048] + bhh_b[g - 2048]);
  }
}

// ---------------- persistent bidirectional LSTM recurrence ----------------
// R8 (resubmit): XCD-LOCAL sync domain. 256 blocks -> 256 CUs (LDS ~91KB
// forces 1 block/CU, so the mapping is a bijection and every XCD gets exactly
// 32 blocks). The first XCD to arrive claims dir0, the second dir1; each
// dir's 32 blocks exchange h(t) through their OWN XCD's L2 (plain
// write-through stores + buffer_inv sc1 + plain reloads) instead of
// agent-scope LLC traffic. Out-atomics (LLC acks that in-order vmcnt drains
// must wait on) are buffered 8 steps in LDS and flushed every 8th step. x is
// staged via LDS (1x per block instead of 4x per wave). Unclaimed XCDs'
// blocks spin on VALU FMA chains to hold SCLK up (DPM hedge).
__global__ __launch_bounds__(256, 1) void lstm_rec(const u16* __restrict__ X,
                                                   const u16* __restrict__ Wih,
                                                   const u16* __restrict__ Whh,
                                                   const float* __restrict__ bias,
                                                   const int* __restrict__ lengths,
                                                   u32* __restrict__ hbuf,
                                                   float* __restrict__ out,
                                                   int* __restrict__ ctl) {
  const int tid = threadIdx.x, lane = tid & 63, wid = tid >> 6;
  const int quad = lane >> 4, l15 = lane & 15;

  __shared__ alignas(16) u16 h_l[32 * HROW];       // 33,024 B  staged h(t)
  __shared__ alignas(16) u16 x_l[32 * HROW];       // 33,024 B  staged x(t)
  __shared__ float pre[4][32][16];                 //  8,192 B
  __shared__ float s_out[8 * 512];                 // 16,384 B  out buffer
  __shared__ int len_s[32];
  __shared__ int s_dir, s_slice, s_done;

  // ---- XCD claim: ctl[0..7]=roster, ctl[8..15]=dirAssign(+1), ctl[16]=dirCtr,
  //      ctl[17]=doneFlag ----
  if (tid == 0) {
    int xcc;
    asm volatile("s_getreg_b32 %0, hwreg(HW_REG_XCC_ID)" : "=s"(xcc));
    xcc &= 7;
    int slot = __hip_atomic_fetch_add(&ctl[xcc], 1, __ATOMIC_RELAXED,
                                      __HIP_MEMORY_SCOPE_AGENT);
    int mydir;
    if (slot == 0) {
      int d = __hip_atomic_fetch_add(&ctl[16], 1, __ATOMIC_RELAXED,
                                     __HIP_MEMORY_SCOPE_AGENT);
      mydir = (d < 2) ? d : 2;
      __hip_atomic_store(&ctl[8 + xcc], mydir + 1, __ATOMIC_RELAXED,
                         __HIP_MEMORY_SCOPE_AGENT);
    } else if (slot < 32) {
      int v;
      do {
        v = __hip_atomic_load(&ctl[8 + xcc], __ATOMIC_RELAXED,
                              __HIP_MEMORY_SCOPE_AGENT);
        if (v == 0) __builtin_amdgcn_s_sleep(2);
      } while (v == 0);
      mydir = v - 1;
    } else {
      mydir = 3;   // overflow block (shouldn't happen with 256-grid bijection)
    }
    s_dir = mydir;
    s_slice = (slot < 32) ? slot : 0;
    s_done = 0;
  }
  __syncthreads();

  if (s_dir == 3) return;
  if (s_dir == 2) {
    // ---- filler: VALU busy-work to hold SCLK until workers finish ----
    float a0 = tid * 0.5f + 1.f, a1 = tid * 0.25f + 2.f;
    float a2 = tid * 0.125f + 3.f, a3 = tid * 0.0625f + 4.f;
    for (;;) {
#pragma unroll 64
      for (int i = 0; i < 512; ++i) {
        a0 = __builtin_fmaf(a0, 0.9999999f, 1e-9f);
        a1 = __builtin_fmaf(a1, 0.9999998f, 2e-9f);
        a2 = __builtin_fmaf(a2, 0.9999997f, 3e-9f);
        a3 = __builtin_fmaf(a3, 0.9999996f, 4e-9f);
      }
      if (tid == 0)
        *(volatile int*)&s_done = __hip_atomic_load(&ctl[17], __ATOMIC_RELAXED,
                                                    __HIP_MEMORY_SCOPE_AGENT);
      if (*(volatile int*)&s_done) break;
    }
    if (a0 + a1 + a2 + a3 == 3.14159f) out[0] = a0;   // unreachable sink
    return;
  }

  const int dir = s_dir, slice = s_slice, c0 = slice * 16;

  if (tid < 32) len_s[tid] = lengths[tid];

  // B-fragments (resident whole loop): wave `wid` owns gate `wid` (i/f/g/o),
  // 16 gate cols. B[k][n] layout: n = l15, k = ks*32 + quad*8 + j.
  bf16x8 bh[16], bxw[16];
  {
    const size_t wrow = (size_t)(dir * 2048 + wid * 512 + c0 + l15) * 512 + quad * 8;
#pragma unroll
    for (int ks = 0; ks < 16; ++ks) {
      bh[ks]  = *(const bf16x8*)(Whh + wrow + (size_t)ks * 32);
      bxw[ks] = *(const bf16x8*)(Wih + wrow + (size_t)ks * 32);
    }
  }
  __syncthreads();   // len_s ready

  const int b0 = tid >> 4, colv = tid & 15, b1 = b0 + 16;
  const int hcol = c0 + colv;
  const float bi  = bias[dir * 2048 + 0 * 512 + hcol];
  const float bfv = bias[dir * 2048 + 1 * 512 + hcol];
  const float bg  = bias[dir * 2048 + 2 * 512 + hcol];
  const float bo  = bias[dir * 2048 + 3 * 512 + hcol];

  float hreg0 = 0.f, hreg1 = 0.f, creg0 = 0.f, creg1 = 0.f;
  const int len0 = len_s[b0], len1 = len_s[b1];
  const int xr = tid >> 3, seg = tid & 7;     // x staging: row, 16B-chunk id
  const int lenxr = len_s[xr];

  for (int t = 0; t < T_LEN; ++t) {
    u32* cur = hbuf + (size_t)(((t & 1) * 2 + dir) * 16384);
    u32* nxt = hbuf + (size_t)((((t + 1) & 1) * 2 + dir) * 16384);

    // ---- issue x tile loads (cooperative: 32KB/block, once) ----
    int ttx = (dir == 0) ? t : (lenxr - 1 - t);  if (ttx < 0) ttx = 0;
    const u16* xg = X + ((size_t)ttx * 32 + xr) * 512;
    bf16x8 xv[8];
#pragma unroll
    for (int k = 0; k < 8; ++k)
      xv[k] = *(const bf16x8*)(xg + k * 64 + seg * 8);

    // ---- issue staged h loads (64 dwords/thread, L2-local) ----
    u64 stg[32];
#pragma unroll
    for (int j = 0; j < 32; ++j)
      stg[j] = *(const u64*)(cur + j * 512 + tid * 2);

    // ---- write x into LDS (vmcnt in-order: waits only the 8 x loads) ----
#pragma unroll
    for (int k = 0; k < 8; ++k)
      *(bf16x8*)&x_l[xr * HROW + k * 64 + seg * 8] = xv[k];

    // ---- poll: retry until every word carries tag t ----
    const u64 e2 = ((u64)(u32)t << 32) | (u32)t;
    for (;;) {
      u64 bad = 0;
#pragma unroll
      for (int j = 0; j < 32; ++j) bad |= (stg[j] ^ e2);
      if ((bad & 0x0000FFFF0000FFFFull) == 0) break;
      asm volatile("buffer_inv sc1" ::: "memory");   // L1 invalidate, reread L2
#pragma unroll
      for (int j = 0; j < 32; ++j)
        stg[j] = *(const u64*)(cur + j * 512 + tid * 2);
    }

    // ---- unpack h payload into padded LDS image (row j = batch j) ----
#pragma unroll
    for (int j = 0; j < 32; ++j) {
      u32 d0 = (u32)stg[j], d1 = (u32)(stg[j] >> 32);
      *(u32*)&h_l[j * HROW + tid * 2] = (d0 >> 16) | (d1 & 0xFFFF0000u);
    }
    __syncthreads();   // B1: x_l + h_l ready

    // ---- MFMAs from LDS fragments (4 accs: 16-deep chains for ILP) ----
    f32x4 a0x = {0.f,0.f,0.f,0.f}, a1x = {0.f,0.f,0.f,0.f};
    f32x4 a0h = {0.f,0.f,0.f,0.f}, a1h = {0.f,0.f,0.f,0.f};
    const u16* xl0 = x_l + (size_t)l15 * HROW + quad * 8;
    const u16* xl1 = x_l + (size_t)(16 + l15) * HROW + quad * 8;
    const u16* hl0 = h_l + (size_t)l15 * HROW + quad * 8;
    const u16* hl1 = h_l + (size_t)(16 + l15) * HROW + quad * 8;
#pragma unroll
    for (int ks = 0; ks < 16; ++ks) {
      a0x = __builtin_amdgcn_mfma_f32_16x16x32_bf16(*(const bf16x8*)(xl0 + ks * 32), bxw[ks], a0x, 0, 0, 0);
      a1x = __builtin_amdgcn_mfma_f32_16x16x32_bf16(*(const bf16x8*)(xl1 + ks * 32), bxw[ks], a1x, 0, 0, 0);
      a0h = __builtin_amdgcn_mfma_f32_16x16x32_bf16(*(const bf16x8*)(hl0 + ks * 32), bh[ks],  a0h, 0, 0, 0);
      a1h = __builtin_amdgcn_mfma_f32_16x16x32_bf16(*(const bf16x8*)(hl1 + ks * 32), bh[ks],  a1h, 0, 0, 0);
    }
    f32x4 acc0 = a0x + a0h, acc1 = a1x + a1h;
    // C/D layout: row (=batch in tile) = quad*4+r, col (=gate col) = l15
#pragma unroll
    for (int r = 0; r < 4; ++r) {
      pre[wid][quad * 4 + r][l15]      = acc0[r];
      pre[wid][16 + quad * 4 + r][l15] = acc1[r];
    }
    __syncthreads();   // B2: pre ready

    // ---- cell update (per-thread state in registers) ----
    float hn0 = 0.f, hn1 = 0.f;
    if (t < len0) {
      float gi = pre[0][b0][colv] + bi,  gf = pre[1][b0][colv] + bfv;
      float gg = pre[2][b0][colv] + bg,  go = pre[3][b0][colv] + bo;
      float cn = sigm(gf) * creg0 + sigm(gi) * tanh_s(gg);
      hn0 = sigm(go) * tanh_s(cn);
      creg0 = cn; hreg0 = hn0;
    }
    if (t < len1) {
      float gi = pre[0][b1][colv] + bi,  gf = pre[1][b1][colv] + bfv;
      float gg = pre[2][b1][colv] + bg,  go = pre[3][b1][colv] + bo;
      float cn = sigm(gf) * creg1 + sigm(gi) * tanh_s(gg);
      hn1 = sigm(go) * tanh_s(cn);
      creg1 = cn; hreg1 = hn1;
    }

    // ---- publish tagged h(t+1): plain stores -> XCD-local L2 ----
    const u32 tag = (u32)(t + 1);
    nxt[(size_t)b0 * 512 + hcol] = ((u32)f2bf(hreg0) << 16) | tag;
    nxt[(size_t)b1 * 512 + hcol] = ((u32)f2bf(hreg1) << 16) | tag;
    asm volatile("" ::: "memory");

    // ---- out accumulation: buffer 8 steps in LDS, flush 1/8 steps ----
    s_out[(t & 7) * 512 + tid]       = hn0;
    s_out[(t & 7) * 512 + 256 + tid] = hn1;
    if ((t & 7) == 7) {
#pragma unroll
      for (int k = 0; k < 8; ++k) {
        int ts = t - 7 + k;
        if (ts < len0) {
          int tt = (dir == 0) ? ts : (len0 - 1 - ts);
          atomicAdd(out + (size_t)(tt * 32 + b0) * 512 + hcol, s_out[k * 512 + tid]);
        }
        if (ts < len1) {
          int tt = (dir == 0) ? ts : (len1 - 1 - ts);
          atomicAdd(out + (size_t)(tt * 32 + b1) * 512 + hcol, s_out[k * 512 + 256 + tid]);
        }
      }
    }
  }

  // finals: h_n (2,B,H), c_n (2,B,H)
  out[HO + (size_t)dir * 16384 + (size_t)b0 * 512 + hcol] = hreg0;
  out[HO + (size_t)dir * 16384 + (size_t)b1 * 512 + hcol] = hreg1;
  out[CO + (size_t)dir * 16384 + (size_t)b0 * 512 + hcol] = creg0;
  out[CO + (size_t)dir * 16384 + (size_t)b1 * 512 + hcol] = creg1;

  // release fillers (first finisher is enough; dirs end in lockstep)
  if (tid == 0)
    __hip_atomic_store(&ctl[17], 1, __ATOMIC_RELAXED, __HIP_MEMORY_SCOPE_AGENT);
}

extern "C" void kernel_launch(void* const* d_in, const int* in_sizes, int n_in,
                              void* d_out, int out_size, void* d_ws, size_t ws_size,
                              hipStream_t stream) {
  const float* x     = (const float*)d_in[0];
  const int*   lens  = (const int*)d_in[1];
  const float* wih_f = (const float*)d_in[2];
  const float* whh_f = (const float*)d_in[3];
  const float* bih_f = (const float*)d_in[4];
  const float* bhh_f = (const float*)d_in[5];
  const float* wih_b = (const float*)d_in[6];
  const float* whh_b = (const float*)d_in[7];
  const float* bih_b = (const float*)d_in[8];
  const float* bhh_b = (const float*)d_in[9];
  float* out = (float*)d_out;
  char* ws = (char*)d_ws;

  u16*   xb   = (u16*)(ws + O_X);
  u16*   Wih  = (u16*)(ws + O_WIH);
  u16*   Whh  = (u16*)(ws + O_WHH);
  float* bias = (float*)(ws + O_BIAS);
  u32*   hbuf = (u32*)(ws + O_HBUF);
  int*   ctl  = (int*)(ws + O_CTL);

  hipMemsetAsync(hbuf, 0, 262144 + 512, stream);           // h tags + ctl
  hipMemsetAsync(d_out, 0, (size_t)out_size * 4, stream);  // out accumulated via atomics

  cast_x_k<<<19200, 256, 0, stream>>>((const float4*)x, xb);
  prep_w_k<<<8192, 256, 0, stream>>>(wih_f, whh_f, bih_f, bhh_f,
                                     wih_b, whh_b, bih_b, bhh_b, Wih, Whh, bias);
  lstm_rec<<<256, 256, 0, stream>>>(xb, Wih, Whh, bias, lens, hbuf, out, ctl);
}

// Round 4
// 11020.304 us; speedup vs baseline: 1.5048x; 1.5048x over previous
//
#include <hip/hip_runtime.h>
#include <cstdint>
#include <cstddef>

typedef unsigned short u16;
typedef unsigned int u32;
typedef unsigned long long u64;
typedef short bf16x8 __attribute__((ext_vector_type(8)));
typedef float f32x4 __attribute__((ext_vector_type(4)));
typedef unsigned short u16x4 __attribute__((ext_vector_type(4)));

#define T_LEN 1200

// workspace byte offsets (all 256-aligned). Total ~48.0 MB.
#define O_X     0ull           // x bf16: 38400*512*2        = 39,321,600
#define O_WIH   39321600ull    // W_ih cat bf16: 4096*512*2  =  4,194,304
#define O_WHH   43515904ull    // W_hh cat bf16: 4096*512*2  =  4,194,304
#define O_BIAS  47710208ull    // bias cat f32: 4096*4       =     16,384
#define O_HBUF  47726592ull    // tagged h dwords: 2 par * 2 dir * 32*512 * 4B = 262,144
#define WS_NEED 47988736ull

#define HO 19660800ull   // h_n offset in d_out (floats)
#define CO 19693568ull   // c_n offset in d_out (floats)

#define HROW 516         // padded LDS row stride (u16 elems): +4 pad -> cheap banks

__device__ __forceinline__ u16 f2bf(float f) {
  union { float f; unsigned u; } v; v.f = f;
  unsigned r = v.u + 0x7FFFu + ((v.u >> 16) & 1u);
  return (u16)(r >> 16);
}
__device__ __forceinline__ float sigm(float x) { return 1.f / (1.f + __expf(-x)); }
__device__ __forceinline__ float tanh_s(float x) {
  float ax = fabsf(x);
  float e = __expf(-2.f * ax);          // in (0,1], no overflow
  float t = (1.f - e) / (1.f + e);
  return x < 0.f ? -t : t;
}

// device-coherent 8B load / 4B store (global_load/store with sc0 sc1, LLC-direct)
__device__ __forceinline__ u64 ld_dev64(const u32* p) {
  return __hip_atomic_load((const u64*)p, __ATOMIC_RELAXED, __HIP_MEMORY_SCOPE_AGENT);
}
__device__ __forceinline__ void st_dev32(u32* p, unsigned v) {
  __hip_atomic_store(p, v, __ATOMIC_RELAXED, __HIP_MEMORY_SCOPE_AGENT);
}

// ---------------- cast x (f32 -> bf16), 4 elems/thread ----------------
__global__ __launch_bounds__(256) void cast_x_k(const float4* __restrict__ x,
                                                u16* __restrict__ xb) {
  int i = blockIdx.x * 256 + threadIdx.x;   // 4,915,200 threads
  float4 v = x[i];
  u16x4 o;
  o.x = f2bf(v.x); o.y = f2bf(v.y); o.z = f2bf(v.z); o.w = f2bf(v.w);
  *(u16x4*)(xb + (size_t)i * 4) = o;
}

// ---------------- concat + cast weights, fold biases ----------------
__global__ __launch_bounds__(256) void prep_w_k(
    const float* __restrict__ wih_f, const float* __restrict__ whh_f,
    const float* __restrict__ bih_f, const float* __restrict__ bhh_f,
    const float* __restrict__ wih_b, const float* __restrict__ whh_b,
    const float* __restrict__ bih_b, const float* __restrict__ bhh_b,
    u16* __restrict__ Wih, u16* __restrict__ Whh, float* __restrict__ bias) {
  int tid = blockIdx.x * 256 + threadIdx.x;   // 0 .. 4096*512-1
  int g = tid >> 9;
  float vi, vh;
  if (g < 2048) { vi = wih_f[tid]; vh = whh_f[tid]; }
  else { int t2 = tid - (2048 * 512); vi = wih_b[t2]; vh = whh_b[t2]; }
  Wih[tid] = f2bf(vi);
  Whh[tid] = f2bf(vh);
  if ((tid & 511) == 0) {
    bias[g] = (g < 2048) ? (bih_f[g] + bhh_f[g]) : (bih_b[g - 2048] + bhh_b[g - 2048]);
  }
}

// ---------------- persistent bidirectional LSTM recurrence ----------------
// R9: R7's LLC tagged-payload exchange (proven), restructured so the ONLY
// serial vmem wait per step is the h poll round trip:
//  - x(t+1) PREFETCHED into registers during step t: step t's x-MFMAs read
//    registers (no vmcnt wait) and issue entirely under the poll's shadow.
//    Previously the x-path vmcnt stacked behind the prior step's publish
//    stores and atomic acks (in-order retirement).
//  - out-atomics buffered 8 steps in LDS, flushed in bursts (R8-proven piece:
//    FETCH_SIZE 844->33 MB — scattered per-step RMWs were thrashing LLC
//    lines to HBM). Acks retire under later polls, off the chain.
//  - 4 independent MFMA accumulator chains (dependent-MFMA latency hiding).
// All R8 XCD/L2/filler machinery reverted (regressed: L2 sweep + buffer_inv
// storms; fillers did not raise SCLK — inferred ~750 MHz in both runs).
__global__ __launch_bounds__(256, 1) void lstm_rec(const u16* __restrict__ X,
                                                   const u16* __restrict__ Wih,
                                                   const u16* __restrict__ Whh,
                                                   const float* __restrict__ bias,
                                                   const int* __restrict__ lengths,
                                                   u32* __restrict__ hbuf,
                                                   float* __restrict__ out) {
  const int tid = threadIdx.x, lane = tid & 63, wid = tid >> 6;
  const int bx = blockIdx.x;
  const int dir = bx >> 5, slice = bx & 31, c0 = slice * 16;
  const int quad = lane >> 4, l15 = lane & 15;

  __shared__ alignas(16) u16 h_l[32 * HROW];   // staged h(t), padded rows
  __shared__ float pre[4][32][16];
  __shared__ float s_out[8 * 512];             // 8-step out buffer (per-thread slots)
  __shared__ int len_s[32];

  if (tid < 32) len_s[tid] = lengths[tid];

  // B-fragments (resident whole loop): wave `wid` owns gate `wid` (i/f/g/o),
  // 16 gate cols. B[k][n] layout: n = l15, k = ks*32 + quad*8 + j.
  bf16x8 bh[16], bxw[16];
  {
    const size_t wrow = (size_t)(dir * 2048 + wid * 512 + c0 + l15) * 512 + quad * 8;
#pragma unroll
    for (int ks = 0; ks < 16; ++ks) {
      bh[ks]  = *(const bf16x8*)(Whh + wrow + (size_t)ks * 32);
      bxw[ks] = *(const bf16x8*)(Wih + wrow + (size_t)ks * 32);
    }
  }
  __syncthreads();   // len_s ready

  const int b0 = tid >> 4, colv = tid & 15, b1 = b0 + 16;
  const int hcol = c0 + colv;
  const float bi  = bias[dir * 2048 + 0 * 512 + hcol];
  const float bfv = bias[dir * 2048 + 1 * 512 + hcol];
  const float bg  = bias[dir * 2048 + 2 * 512 + hcol];
  const float bo  = bias[dir * 2048 + 3 * 512 + hcol];

  float hreg0 = 0.f, hreg1 = 0.f, creg0 = 0.f, creg1 = 0.f;
  const int len0 = len_s[b0], len1 = len_s[b1];
  const int ba = l15, bb = 16 + l15;
  const int lena = len_s[ba], lenb = len_s[bb];

  // ---- prologue: prefetch x(0) fragments into registers ----
  bf16x8 ax0[16], ax1[16];
  {
    int tta = (dir == 0) ? 0 : (lena - 1);  if (tta < 0) tta = 0;
    int ttb = (dir == 0) ? 0 : (lenb - 1);  if (ttb < 0) ttb = 0;
    const u16* xrow0 = X + ((size_t)tta * 32 + ba) * 512 + quad * 8;
    const u16* xrow1 = X + ((size_t)ttb * 32 + bb) * 512 + quad * 8;
#pragma unroll
    for (int ks = 0; ks < 16; ++ks) {
      ax0[ks] = *(const bf16x8*)(xrow0 + (size_t)ks * 32);
      ax1[ks] = *(const bf16x8*)(xrow1 + (size_t)ks * 32);
    }
  }

  for (int t = 0; t < T_LEN; ++t) {
    u32* cur = hbuf + (size_t)(((t & 1) * 2 + dir) * 16384);
    u32* nxt = hbuf + (size_t)((((t + 1) & 1) * 2 + dir) * 16384);

    // ---- issue h poll loads FIRST (the long pole) ----
    u64 stg[32];
#pragma unroll
    for (int j = 0; j < 32; ++j)
      stg[j] = ld_dev64(cur + j * 512 + tid * 2);

    // ---- x-part MFMAs: registers only (prefetched last step) — issue
    //      entirely under the poll round trip, zero vmem wait ----
    f32x4 a0x = {0.f,0.f,0.f,0.f}, a1x = {0.f,0.f,0.f,0.f};
#pragma unroll
    for (int ks = 0; ks < 16; ++ks) {
      a0x = __builtin_amdgcn_mfma_f32_16x16x32_bf16(ax0[ks], bxw[ks], a0x, 0, 0, 0);
      a1x = __builtin_amdgcn_mfma_f32_16x16x32_bf16(ax1[ks], bxw[ks], a1x, 0, 0, 0);
    }

    // ---- poll: retry until every word carries tag t ----
    const u64 e2 = ((u64)(u32)t << 32) | (u32)t;
    for (;;) {
      u64 bad = 0;
#pragma unroll
      for (int j = 0; j < 32; ++j) bad |= (stg[j] ^ e2);
      if ((bad & 0x0000FFFF0000FFFFull) == 0) break;
#pragma unroll
      for (int j = 0; j < 32; ++j)
        stg[j] = ld_dev64(cur + j * 512 + tid * 2);
    }

    // ---- prefetch x(t+1): issues now, retires under cell+publish+next poll.
    //      WAR on ax is safe: this iter's x-MFMAs already issued (in-order). ----
    {
      int tn = t + 1;
      int tta = (dir == 0) ? (tn < T_LEN ? tn : T_LEN - 1) : (lena - 1 - tn);
      int ttb = (dir == 0) ? (tn < T_LEN ? tn : T_LEN - 1) : (lenb - 1 - tn);
      if (tta < 0) tta = 0;
      if (ttb < 0) ttb = 0;
      const u16* xrow0 = X + ((size_t)tta * 32 + ba) * 512 + quad * 8;
      const u16* xrow1 = X + ((size_t)ttb * 32 + bb) * 512 + quad * 8;
#pragma unroll
      for (int ks = 0; ks < 16; ++ks) {
        ax0[ks] = *(const bf16x8*)(xrow0 + (size_t)ks * 32);
        ax1[ks] = *(const bf16x8*)(xrow1 + (size_t)ks * 32);
      }
    }

    // ---- unpack h payload into padded LDS image (row j = batch j) ----
#pragma unroll
    for (int j = 0; j < 32; ++j) {
      u32 d0 = (u32)stg[j], d1 = (u32)(stg[j] >> 32);
      *(u32*)&h_l[j * HROW + tid * 2] = (d0 >> 16) | (d1 & 0xFFFF0000u);
    }
    __syncthreads();   // B1: h image ready

    // ---- h-part MFMAs from LDS fragments (2 more independent chains) ----
    f32x4 a0h = {0.f,0.f,0.f,0.f}, a1h = {0.f,0.f,0.f,0.f};
    const u16* hl0 = h_l + (size_t)l15 * HROW + quad * 8;
    const u16* hl1 = h_l + (size_t)(16 + l15) * HROW + quad * 8;
#pragma unroll
    for (int ks = 0; ks < 16; ++ks) {
      bf16x8 f0 = *(const bf16x8*)(hl0 + ks * 32);
      bf16x8 f1 = *(const bf16x8*)(hl1 + ks * 32);
      a0h = __builtin_amdgcn_mfma_f32_16x16x32_bf16(f0, bh[ks], a0h, 0, 0, 0);
      a1h = __builtin_amdgcn_mfma_f32_16x16x32_bf16(f1, bh[ks], a1h, 0, 0, 0);
    }
    f32x4 acc0 = a0x + a0h, acc1 = a1x + a1h;
    // C/D layout: row (=batch in tile) = quad*4+r, col (=gate col) = l15
#pragma unroll
    for (int r = 0; r < 4; ++r) {
      pre[wid][quad * 4 + r][l15]      = acc0[r];
      pre[wid][16 + quad * 4 + r][l15] = acc1[r];
    }
    __syncthreads();   // B2: pre ready (also fences h_l reads vs next-iter writes)

    // ---- cell update (per-thread state in registers) ----
    float hn0 = 0.f, hn1 = 0.f;
    if (t < len0) {
      float gi = pre[0][b0][colv] + bi,  gf = pre[1][b0][colv] + bfv;
      float gg = pre[2][b0][colv] + bg,  go = pre[3][b0][colv] + bo;
      float cn = sigm(gf) * creg0 + sigm(gi) * tanh_s(gg);
      hn0 = sigm(go) * tanh_s(cn);
      creg0 = cn; hreg0 = hn0;
    }
    if (t < len1) {
      float gi = pre[0][b1][colv] + bi,  gf = pre[1][b1][colv] + bfv;
      float gg = pre[2][b1][colv] + bg,  go = pre[3][b1][colv] + bo;
      float cn = sigm(gf) * creg1 + sigm(gi) * tanh_s(gg);
      hn1 = sigm(go) * tanh_s(cn);
      creg1 = cn; hreg1 = hn1;
    }

    // ---- publish tagged h(t+1): fire-and-forget LLC stores ----
    const u32 tag = (u32)(t + 1);
    st_dev32(nxt + (size_t)b0 * 512 + hcol, ((u32)f2bf(hreg0) << 16) | tag);
    st_dev32(nxt + (size_t)b1 * 512 + hcol, ((u32)f2bf(hreg1) << 16) | tag);

    // ---- out accumulation: buffer 8 steps (private LDS slots), burst-flush.
    //      Atomic acks retire under later polls, off the critical chain. ----
    s_out[(t & 7) * 512 + tid]       = hn0;
    s_out[(t & 7) * 512 + 256 + tid] = hn1;
    if ((t & 7) == 7) {
#pragma unroll
      for (int k = 0; k < 8; ++k) {
        int ts = t - 7 + k;
        if (ts < len0) {
          int tt = (dir == 0) ? ts : (len0 - 1 - ts);
          atomicAdd(out + (size_t)(tt * 32 + b0) * 512 + hcol, s_out[k * 512 + tid]);
        }
        if (ts < len1) {
          int tt = (dir == 0) ? ts : (len1 - 1 - ts);
          atomicAdd(out + (size_t)(tt * 32 + b1) * 512 + hcol, s_out[k * 512 + 256 + tid]);
        }
      }
    }
  }

  // finals: h_n (2,B,H), c_n (2,B,H)
  out[HO + (size_t)dir * 16384 + (size_t)b0 * 512 + hcol] = hreg0;
  out[HO + (size_t)dir * 16384 + (size_t)b1 * 512 + hcol] = hreg1;
  out[CO + (size_t)dir * 16384 + (size_t)b0 * 512 + hcol] = creg0;
  out[CO + (size_t)dir * 16384 + (size_t)b1 * 512 + hcol] = creg1;
}

extern "C" void kernel_launch(void* const* d_in, const int* in_sizes, int n_in,
                              void* d_out, int out_size, void* d_ws, size_t ws_size,
                              hipStream_t stream) {
  const float* x     = (const float*)d_in[0];
  const int*   lens  = (const int*)d_in[1];
  const float* wih_f = (const float*)d_in[2];
  const float* whh_f = (const float*)d_in[3];
  const float* bih_f = (const float*)d_in[4];
  const float* bhh_f = (const float*)d_in[5];
  const float* wih_b = (const float*)d_in[6];
  const float* whh_b = (const float*)d_in[7];
  const float* bih_b = (const float*)d_in[8];
  const float* bhh_b = (const float*)d_in[9];
  float* out = (float*)d_out;
  char* ws = (char*)d_ws;

  u16*   xb   = (u16*)(ws + O_X);
  u16*   Wih  = (u16*)(ws + O_WIH);
  u16*   Whh  = (u16*)(ws + O_WHH);
  float* bias = (float*)(ws + O_BIAS);
  u32*   hbuf = (u32*)(ws + O_HBUF);

  hipMemsetAsync(hbuf, 0, 262144, stream);                 // tag 0 == h(0) == 0
  hipMemsetAsync(d_out, 0, (size_t)out_size * 4, stream);  // out accumulated via atomics

  cast_x_k<<<19200, 256, 0, stream>>>((const float4*)x, xb);
  prep_w_k<<<8192, 256, 0, stream>>>(wih_f, whh_f, bih_f, bhh_f,
                                     wih_b, whh_b, bih_b, bhh_b, Wih, Whh, bias);
  lstm_rec<<<64, 256, 0, stream>>>(xb, Wih, Whh, bias, lens, hbuf, out);
}